// Round 6
// baseline (229.677 us; speedup 1.0000x reference)
//
#include <hip/hip_runtime.h>

#define B_ 4
#define S_ 2048
#define D_ 512
#define H_ 8

typedef __attribute__((ext_vector_type(8))) __bf16 bf16x8;
typedef __attribute__((ext_vector_type(4))) float f32x4;

#define NEGBIG  -1.442695040e9f          // -1e9 * log2(e): masks live in exp2 domain
#define QSCALE  0.18033688011112042f     // 0.125 * log2(e) folded into Q

// pack two floats -> two bf16 (RNE-ish, ties-up): 2 adds + 1 v_perm
__device__ __forceinline__ unsigned pack_rn(float a, float b) {
    union { float f; unsigned u; } ua, ub; ua.f = a; ub.f = b;
    return __builtin_amdgcn_perm(ub.u + 0x8000u, ua.u + 0x8000u, 0x07060302u);
}

// ---------------------------------------------------------------------------
// fp32 -> bf16 cast of activations (row-major unchanged).
// ---------------------------------------------------------------------------
__global__ __launch_bounds__(256) void cast_x(
    const float* __restrict__ q, const float* __restrict__ v,
    unsigned short* __restrict__ xq, unsigned short* __restrict__ xv)
{
    const float* src = blockIdx.z ? v : q;
    unsigned short* dst = blockIdx.z ? xv : xq;
    int i = (blockIdx.x * 256 + threadIdx.x) * 8;
    float4 f0 = *(const float4*)&src[i];
    float4 f1 = *(const float4*)&src[i + 4];
    uint4 o;
    o.x = pack_rn(f0.x, f0.y); o.y = pack_rn(f0.z, f0.w);
    o.z = pack_rn(f1.x, f1.y); o.w = pack_rn(f1.z, f1.w);
    *(uint4*)&dst[i] = o;
}

// ---------------------------------------------------------------------------
// Coalesced weight cast+transpose: Wt[n][k] = bf16(W[k][n]), via LDS tile.
// ---------------------------------------------------------------------------
__global__ __launch_bounds__(256) void cast_wt(
    const float* __restrict__ Wq, const float* __restrict__ Wk,
    const float* __restrict__ Wv, const float* __restrict__ Wo,
    unsigned short* __restrict__ Tq, unsigned short* __restrict__ Tk,
    unsigned short* __restrict__ Tv, unsigned short* __restrict__ To)
{
    int z = blockIdx.z;
    const float* W = (z == 0) ? Wq : (z == 1) ? Wk : (z == 2) ? Wv : Wo;
    unsigned short* T = (z == 0) ? Tq : (z == 1) ? Tk : (z == 2) ? Tv : To;
    int n0 = blockIdx.x * 64, k0 = blockIdx.y * 64;
    int tid = threadIdx.x;

    __shared__ float Ts[64][69];
    #pragma unroll
    for (int it = 0; it < 4; it++) {
        int lin = tid + it * 256;
        int kr = lin >> 4, c4 = (lin & 15) * 4;
        float4 v = *(const float4*)&W[(k0 + kr) * 512 + n0 + c4];
        Ts[kr][c4 + 0] = v.x; Ts[kr][c4 + 1] = v.y;
        Ts[kr][c4 + 2] = v.z; Ts[kr][c4 + 3] = v.w;
    }
    __syncthreads();
    int n = tid >> 2, kc = tid & 3;
    unsigned p[8];
    #pragma unroll
    for (int j = 0; j < 8; j++)
        p[j] = pack_rn(Ts[kc * 16 + 2 * j][n], Ts[kc * 16 + 2 * j + 1][n]);
    unsigned short* dst = &T[(n0 + n) * 512 + k0 + kc * 16];
    *(uint4*)dst       = *(uint4*)&p[0];
    *(uint4*)(dst + 8) = *(uint4*)&p[4];
}

// ---------------------------------------------------------------------------
// QKV projection GEMM, all-bf16 staging, 128x128 tile, 4 waves (2x2 of 64).
// z=0 (Q): A=Wtq (m=feature), B=Xq (n=s) -> (bh,s,d), scaled by 0.125*log2e.
// z=1 (K): A=Wtk, B=Xv -> (bh,s,d).
// z=2 (V): A=Xv (m=s), B=Wtv (n=feature) -> transposed (bh,d,s).
// ---------------------------------------------------------------------------
__global__ __launch_bounds__(256) void proj_qkv_mfma(
    const unsigned short* __restrict__ Xq, const unsigned short* __restrict__ Xv,
    const unsigned short* __restrict__ Wtq, const unsigned short* __restrict__ Wtk,
    const unsigned short* __restrict__ Wtv,
    const float* __restrict__ bq, const float* __restrict__ bk,
    const float* __restrict__ bv,
    unsigned short* __restrict__ Qb, unsigned short* __restrict__ Kb,
    unsigned short* __restrict__ VtG)
{
    const int z = blockIdx.z;
    const unsigned short* A  = (z == 0) ? Wtq : (z == 1) ? Wtk : Xv;
    const unsigned short* Bm = (z == 0) ? Xq  : (z == 1) ? Xv  : Wtv;
    const float* bias        = (z == 0) ? bq  : (z == 1) ? bk  : bv;
    const int m0 = (z < 2) ? blockIdx.y * 128 : blockIdx.x * 128;
    const int n0 = (z < 2) ? blockIdx.x * 128 : blockIdx.y * 128;

    const int tid = threadIdx.x;
    const int w = tid >> 6, lane = tid & 63;
    const int l15 = lane & 15, quad = lane >> 4;
    const int wm = (w >> 1) * 64, wn = (w & 1) * 64;

    __shared__ unsigned short As[128 * 72];
    __shared__ unsigned short Bs[128 * 72];

    f32x4 acc[4][4];
    #pragma unroll
    for (int i = 0; i < 4; i++)
        #pragma unroll
        for (int j = 0; j < 4; j++) acc[i][j] = (f32x4){0.f, 0.f, 0.f, 0.f};

    for (int k0 = 0; k0 < 512; k0 += 64) {
        __syncthreads();
        #pragma unroll
        for (int it = 0; it < 2; it++) {
            int lin = tid + it * 256;
            int row = lin >> 2, c2 = (lin & 3) * 2;   // 2 of 8 chunks per row
            *(uint4*)&As[row * 72 + c2 * 8]     = *(const uint4*)&A[(m0 + row) * 512 + k0 + c2 * 8];
            *(uint4*)&As[row * 72 + c2 * 8 + 8] = *(const uint4*)&A[(m0 + row) * 512 + k0 + c2 * 8 + 8];
            *(uint4*)&Bs[row * 72 + c2 * 8]     = *(const uint4*)&Bm[(n0 + row) * 512 + k0 + c2 * 8];
            *(uint4*)&Bs[row * 72 + c2 * 8 + 8] = *(const uint4*)&Bm[(n0 + row) * 512 + k0 + c2 * 8 + 8];
        }
        __syncthreads();
        #pragma unroll
        for (int kc = 0; kc < 2; kc++) {
            bf16x8 a[4], bb[4];
            #pragma unroll
            for (int i = 0; i < 4; i++)
                a[i] = *(const bf16x8*)&As[(wm + 16 * i + l15) * 72 + kc * 32 + quad * 8];
            #pragma unroll
            for (int j = 0; j < 4; j++)
                bb[j] = *(const bf16x8*)&Bs[(wn + 16 * j + l15) * 72 + kc * 32 + quad * 8];
            #pragma unroll
            for (int i = 0; i < 4; i++)
                #pragma unroll
                for (int j = 0; j < 4; j++)
                    acc[i][j] = __builtin_amdgcn_mfma_f32_16x16x32_bf16(a[i], bb[j], acc[i][j], 0, 0, 0);
        }
    }

    if (z == 2) {
        #pragma unroll
        for (int j = 0; j < 4; j++) {
            int N = n0 + wn + 16 * j + l15;
            float bv_ = bias[N];
            int h = N >> 6, d = N & 63;
            #pragma unroll
            for (int i = 0; i < 4; i++) {
                int Mb = m0 + wm + 16 * i + quad * 4;
                int b = Mb >> 11, s = Mb & 2047;
                uint2 o;
                o.x = pack_rn(acc[i][j][0] + bv_, acc[i][j][1] + bv_);
                o.y = pack_rn(acc[i][j][2] + bv_, acc[i][j][3] + bv_);
                *(uint2*)&VtG[((b * H_ + h) * 64 + d) * 2048 + s] = o;
            }
        }
    } else {
        unsigned short* dst = (z == 0) ? Qb : Kb;
        const float scale = (z == 0) ? QSCALE : 1.0f;
        #pragma unroll
        for (int j = 0; j < 4; j++) {
            int sg = n0 + wn + 16 * j + l15;
            int b = sg >> 11, s = sg & 2047;
            #pragma unroll
            for (int i = 0; i < 4; i++) {
                int F = m0 + wm + 16 * i + quad * 4;
                int h = F >> 6, d = F & 63;
                float4 b4 = *(const float4*)&bias[F];
                uint2 o;
                o.x = pack_rn((acc[i][j][0] + b4.x) * scale, (acc[i][j][1] + b4.y) * scale);
                o.y = pack_rn((acc[i][j][2] + b4.z) * scale, (acc[i][j][3] + b4.w) * scale);
                *(uint2*)&dst[((b * H_ + h) * 2048 + s) * 64 + d] = o;
            }
        }
    }
}

// ---------------------------------------------------------------------------
// MFMA flash attention. Block = (b,h, 64-q tile), 4 waves x 16q each.
// Grid 32x32 = 1024 blocks (~3/CU, LDS-capped) for latency hiding.
// K AND V staged via double-buffered LDS (register pipeline, ONE barrier per
// 64-key tile). Masks folded into MFMA C-init (exact fp32-quantization
// reproduction), softmax in exp2 domain (log2e folded into Q), P via
// per-wave LDS (C->B layout transform).
// ---------------------------------------------------------------------------
__global__ __launch_bounds__(256, 4) void flash_mfma(
    const unsigned short* __restrict__ Qg, const unsigned short* __restrict__ Kg,
    const unsigned short* __restrict__ VtG, const int* __restrict__ amask,
    unsigned short* __restrict__ ctxB)
{
    const int bh = blockIdx.y, b = bh >> 3, h = bh & 7;
    const int q0 = blockIdx.x * 64;
    const int tid = threadIdx.x;
    const int w = tid >> 6, lane = tid & 63;
    const int l15 = lane & 15, quad = lane >> 4;

    __shared__ unsigned short Ks[2][64 * 72];   // double-buffered K tile [key][d]
    __shared__ unsigned short Vs[2][64 * 72];   // double-buffered Vt tile [d][key]
    __shared__ unsigned short Ps[4][16 * 72];   // per-wave P region [q][key]
    __shared__ float Km[4][64];                 // per-wave key-mask floats

    const int* amask_b = amask + b * 2048;
    unsigned short* pw = &Ps[w][0];

    // Q fragments (B-operand) + query mask, resident. Wave owns 16 q rows.
    const int qrow = q0 + w * 16 + l15;
    bf16x8 qf[2];
    {
        const unsigned short* p = &Qg[(bh * 2048 + qrow) * 64 + quad * 8];
        qf[0] = *(const bf16x8*)p;
        qf[1] = *(const bf16x8*)(p + 32);
    }
    const float mq = amask_b[qrow] ? 0.f : NEGBIG;

    // staging: thread -> (row = tid>>2, 2 chunks at (tid&3)*2) of a 64x64 tile
    const int srow = tid >> 2;
    const int sch  = (tid & 3) * 2;
    const unsigned short* kgb = Kg  + (long)bh * 2048 * 64;
    const unsigned short* vgb = VtG + (long)bh * 64 * 2048;

    // preamble: stage tile 0 into buffer 0
    *(uint4*)&Ks[0][srow * 72 + sch * 8]     = *(const uint4*)&kgb[srow * 64 + sch * 8];
    *(uint4*)&Ks[0][srow * 72 + sch * 8 + 8] = *(const uint4*)&kgb[srow * 64 + sch * 8 + 8];
    *(uint4*)&Vs[0][srow * 72 + sch * 8]     = *(const uint4*)&vgb[srow * 2048 + sch * 8];
    *(uint4*)&Vs[0][srow * 72 + sch * 8 + 8] = *(const uint4*)&vgb[srow * 2048 + sch * 8 + 8];
    int mreg = amask_b[lane];

    f32x4 accO[4];
    #pragma unroll
    for (int dt = 0; dt < 4; dt++) accO[dt] = (f32x4){0.f, 0.f, 0.f, 0.f};
    float mi = -3.0e38f;
    float li = 0.f;

    __syncthreads();

    for (int t = 0; t < 32; t++) {
        const int kt = t * 64;
        const int ktn = (t < 31) ? kt + 64 : kt;
        const int cur = t & 1, nxt = cur ^ 1;

        // [A] issue global loads for NEXT tile into registers
        uint4 ka0 = *(const uint4*)&kgb[(ktn + srow) * 64 + sch * 8];
        uint4 ka1 = *(const uint4*)&kgb[(ktn + srow) * 64 + sch * 8 + 8];
        uint4 va0 = *(const uint4*)&vgb[srow * 2048 + ktn + sch * 8];
        uint4 va1 = *(const uint4*)&vgb[srow * 2048 + ktn + sch * 8 + 8];
        Km[w][lane] = mreg ? 0.f : NEGBIG;
        mreg = amask_b[ktn + lane];

        f32x4 kmf[4];
        #pragma unroll
        for (int nt = 0; nt < 4; nt++)
            kmf[nt] = *(const f32x4*)&Km[w][nt * 16 + quad * 4];

        // [B] QK from LDS buf[cur]: S^T (rows=key, cols=q)
        f32x4 sc[4];
        #pragma unroll
        for (int nt = 0; nt < 4; nt++) {
            sc[nt] = kmf[nt] + mq;   // masks as C-init: exact
            #pragma unroll
            for (int kc = 0; kc < 2; kc++) {
                bf16x8 kf = *(const bf16x8*)&Ks[cur][(nt * 16 + l15) * 72 + kc * 32 + quad * 8];
                sc[nt] = __builtin_amdgcn_mfma_f32_16x16x32_bf16(kf, qf[kc], sc[nt], 0, 0, 0);
            }
        }

        // [C] online softmax (reduce over keys = in-lane + quad shfls)
        {
            float mloc = sc[0][0];
            #pragma unroll
            for (int nt = 0; nt < 4; nt++)
                #pragma unroll
                for (int r = 0; r < 4; r++)
                    mloc = fmaxf(mloc, sc[nt][r]);
            mloc = fmaxf(mloc, __shfl_xor(mloc, 16));
            mloc = fmaxf(mloc, __shfl_xor(mloc, 32));
            float mn = fmaxf(mi, mloc);
            float alpha = __builtin_amdgcn_exp2f(mi - mn);
            float ps = 0.f;
            #pragma unroll
            for (int nt = 0; nt < 4; nt++) {
                float p0 = __builtin_amdgcn_exp2f(sc[nt][0] - mn);
                float p1 = __builtin_amdgcn_exp2f(sc[nt][1] - mn);
                float p2 = __builtin_amdgcn_exp2f(sc[nt][2] - mn);
                float p3 = __builtin_amdgcn_exp2f(sc[nt][3] - mn);
                ps += (p0 + p1) + (p2 + p3);
                int prow = l15 * 72 + nt * 16 + quad * 4;
                *(unsigned*)&pw[prow]     = pack_rn(p0, p1);
                *(unsigned*)&pw[prow + 2] = pack_rn(p2, p3);
            }
            ps += __shfl_xor(ps, 16);
            ps += __shfl_xor(ps, 32);
            li = li * alpha + ps;
            mi = mn;
            #pragma unroll
            for (int dt = 0; dt < 4; dt++) {
                accO[dt][0] *= alpha; accO[dt][1] *= alpha;
                accO[dt][2] *= alpha; accO[dt][3] *= alpha;
            }
        }

        // [D] PV: O^T += Vt (A) x P^T (B)
        {
            bf16x8 pf0 = *(const bf16x8*)&pw[l15 * 72 + quad * 8];
            bf16x8 pf1 = *(const bf16x8*)&pw[l15 * 72 + 32 + quad * 8];
            #pragma unroll
            for (int dt = 0; dt < 4; dt++) {
                bf16x8 vf0 = *(const bf16x8*)&Vs[cur][(dt * 16 + l15) * 72 + quad * 8];
                bf16x8 vf1 = *(const bf16x8*)&Vs[cur][(dt * 16 + l15) * 72 + 32 + quad * 8];
                accO[dt] = __builtin_amdgcn_mfma_f32_16x16x32_bf16(vf0, pf0, accO[dt], 0, 0, 0);
                accO[dt] = __builtin_amdgcn_mfma_f32_16x16x32_bf16(vf1, pf1, accO[dt], 0, 0, 0);
            }
        }

        // [E] commit next tile to LDS (waits the [A] loads), [F] barrier
        *(uint4*)&Ks[nxt][srow * 72 + sch * 8]     = ka0;
        *(uint4*)&Ks[nxt][srow * 72 + sch * 8 + 8] = ka1;
        *(uint4*)&Vs[nxt][srow * 72 + sch * 8]     = va0;
        *(uint4*)&Vs[nxt][srow * 72 + sch * 8 + 8] = va1;
        __syncthreads();
    }

    const float inv = 1.f / li;
    const int obase = (b * 2048 + qrow) * 512 + h * 64 + quad * 4;
    #pragma unroll
    for (int dt = 0; dt < 4; dt++) {
        uint2 o;
        o.x = pack_rn(accO[dt][0] * inv, accO[dt][1] * inv);
        o.y = pack_rn(accO[dt][2] * inv, accO[dt][3] * inv);
        *(uint2*)&ctxB[obase + dt * 16] = o;
    }
}

// ---------------------------------------------------------------------------
// Output projection: out(fp32) = ctx_bf16 @ Wo + bo.
// A=Wto (m=out-feature), B=ctx (n=s) -> epilogue is direct float4 stores.
// ---------------------------------------------------------------------------
__global__ __launch_bounds__(256) void proj_out_mfma(
    const unsigned short* __restrict__ ctxB, const unsigned short* __restrict__ Wto,
    const float* __restrict__ bo, float* __restrict__ out)
{
    const int m0 = blockIdx.y * 128, n0 = blockIdx.x * 128;
    const int tid = threadIdx.x;
    const int w = tid >> 6, lane = tid & 63;
    const int l15 = lane & 15, quad = lane >> 4;
    const int wm = (w >> 1) * 64, wn = (w & 1) * 64;

    __shared__ unsigned short As[128 * 72];
    __shared__ unsigned short Bs[128 * 72];

    f32x4 acc[4][4];
    #pragma unroll
    for (int i = 0; i < 4; i++)
        #pragma unroll
        for (int j = 0; j < 4; j++) acc[i][j] = (f32x4){0.f, 0.f, 0.f, 0.f};

    for (int k0 = 0; k0 < 512; k0 += 64) {
        __syncthreads();
        #pragma unroll
        for (int it = 0; it < 2; it++) {
            int lin = tid + it * 256;
            int row = lin >> 2, c2 = (lin & 3) * 2;
            *(uint4*)&As[row * 72 + c2 * 8]     = *(const uint4*)&Wto[(m0 + row) * 512 + k0 + c2 * 8];
            *(uint4*)&As[row * 72 + c2 * 8 + 8] = *(const uint4*)&Wto[(m0 + row) * 512 + k0 + c2 * 8 + 8];
            *(uint4*)&Bs[row * 72 + c2 * 8]     = *(const uint4*)&ctxB[(n0 + row) * 512 + k0 + c2 * 8];
            *(uint4*)&Bs[row * 72 + c2 * 8 + 8] = *(const uint4*)&ctxB[(n0 + row) * 512 + k0 + c2 * 8 + 8];
        }
        __syncthreads();
        #pragma unroll
        for (int kc = 0; kc < 2; kc++) {
            bf16x8 a[4], bb[4];
            #pragma unroll
            for (int i = 0; i < 4; i++)
                a[i] = *(const bf16x8*)&As[(wm + 16 * i + l15) * 72 + kc * 32 + quad * 8];
            #pragma unroll
            for (int j = 0; j < 4; j++)
                bb[j] = *(const bf16x8*)&Bs[(wn + 16 * j + l15) * 72 + kc * 32 + quad * 8];
            #pragma unroll
            for (int i = 0; i < 4; i++)
                #pragma unroll
                for (int j = 0; j < 4; j++)
                    acc[i][j] = __builtin_amdgcn_mfma_f32_16x16x32_bf16(a[i], bb[j], acc[i][j], 0, 0, 0);
        }
    }

    #pragma unroll
    for (int j = 0; j < 4; j++) {
        int sg = n0 + wn + 16 * j + l15;
        #pragma unroll
        for (int i = 0; i < 4; i++) {
            int F = m0 + wm + 16 * i + quad * 4;
            float4 b4 = *(const float4*)&bo[F];
            float4 vv;
            vv.x = acc[i][j][0] + b4.x;
            vv.y = acc[i][j][1] + b4.y;
            vv.z = acc[i][j][2] + b4.z;
            vv.w = acc[i][j][3] + b4.w;
            *(float4*)&out[sg * 512 + F] = vv;
        }
    }
}

extern "C" void kernel_launch(void* const* d_in, const int* in_sizes, int n_in,
                              void* d_out, int out_size, void* d_ws, size_t ws_size,
                              hipStream_t stream)
{
    const float* query = (const float*)d_in[0];
    const float* value = (const float*)d_in[1];
    const int*   amask = (const int*)d_in[2];
    const float* Wq = (const float*)d_in[3];
    const float* bq = (const float*)d_in[4];
    const float* Wk = (const float*)d_in[5];
    const float* bk = (const float*)d_in[6];
    const float* Wv = (const float*)d_in[7];
    const float* bv = (const float*)d_in[8];
    const float* Wo = (const float*)d_in[9];
    const float* bo = (const float*)d_in[10];
    float* out = (float*)d_out;

    char* ws = (char*)d_ws;
    const size_t MB = 1 << 20;
    unsigned short* Xbq = (unsigned short*)(ws);                  // 8 MB bf16
    unsigned short* Xbv = (unsigned short*)(ws + 8 * MB);         // 8 MB
    unsigned short* Wtq = (unsigned short*)(ws + 16 * MB);        // 0.5 MB each
    unsigned short* Wtk = (unsigned short*)(ws + 16 * MB + MB / 2);
    unsigned short* Wtv = (unsigned short*)(ws + 17 * MB);
    unsigned short* Wto = (unsigned short*)(ws + 17 * MB + MB / 2);
    unsigned short* Qb  = (unsigned short*)(ws + 18 * MB);        // 8 MB (bh,s,d)
    unsigned short* Kb  = (unsigned short*)(ws + 26 * MB);        // 8 MB (bh,s,d)
    unsigned short* VtG = (unsigned short*)(ws + 34 * MB);        // 8 MB (bh,d,s)
    unsigned short* ctx = (unsigned short*)(ws + 42 * MB);        // 8 MB (b*s, h*d)

    cast_x<<<dim3(2048, 1, 2), 256, 0, stream>>>(query, value, Xbq, Xbv);
    cast_wt<<<dim3(8, 8, 4), 256, 0, stream>>>(Wq, Wk, Wv, Wo, Wtq, Wtk, Wtv, Wto);
    proj_qkv_mfma<<<dim3(64, 4, 3), 256, 0, stream>>>(Xbq, Xbv, Wtq, Wtk, Wtv,
                                                      bq, bk, bv, Qb, Kb, VtG);
    flash_mfma<<<dim3(32, 32), 256, 0, stream>>>(Qb, Kb, VtG, amask, ctx);
    proj_out_mfma<<<dim3(64, 4), 256, 0, stream>>>(ctx, Wto, bo, out);
}